// Round 12
// baseline (323.677 us; speedup 1.0000x reference)
//
#include <hip/hip_runtime.h>
#include <stdint.h>

#define SEQ 2048
#define EMB 1024
#define NROWS 4096  // 2 batches * 2048

typedef __bf16 bf16x8 __attribute__((ext_vector_type(8)));
typedef float f32x4 __attribute__((ext_vector_type(4)));
typedef unsigned short ushort8 __attribute__((ext_vector_type(8)));

__device__ __forceinline__ unsigned short f2bf(float f) {
  unsigned int u = __float_as_uint(f);
  u += 0x7fffu + ((u >> 16) & 1u);
  return (unsigned short)(u >> 16);
}

__device__ __forceinline__ float bf2f(unsigned short h) {
  return __uint_as_float((unsigned int)h << 16);
}

__device__ __forceinline__ f32x4 mfma16(bf16x8 a, bf16x8 b, f32x4 c) {
  return __builtin_amdgcn_mfma_f32_16x16x32_bf16(a, b, c, 0, 0, 0);
}

// async global->LDS, 16B per lane; lds dest = wave-uniform base + lane*16
__device__ __forceinline__ void async_load16(const void* g, void* l) {
  auto gp = reinterpret_cast<__attribute__((address_space(1))) void*>(
      reinterpret_cast<uintptr_t>(g));
  auto lp = reinterpret_cast<__attribute__((address_space(3))) void*>(
      reinterpret_cast<uintptr_t>(l));
  __builtin_amdgcn_global_load_lds(gp, lp, 16, 0, 0);
}

// ------- prep: fp32->bf16 convert of both inputs + 8x weight transpose, ONE launch -------
// blocks [0, 8192): cvt (4 float4 per thread-block row); blocks [8192, 10240): wtrans.
__global__ __launch_bounds__(256) void prep(const float* __restrict__ t,
                                            const float* __restrict__ s,
                                            unsigned short* __restrict__ tb,
                                            unsigned short* __restrict__ sb,
                                            const float* __restrict__ W0,
                                            const float* __restrict__ W1,
                                            const float* __restrict__ W2,
                                            const float* __restrict__ W3,
                                            const float* __restrict__ W4,
                                            const float* __restrict__ W5,
                                            const float* __restrict__ W6,
                                            const float* __restrict__ W7,
                                            unsigned short* __restrict__ Wt) {
  const int bx = blockIdx.x;
  if (bx < 8192) {
    int i = bx * 256 + threadIdx.x;
    const float* x; unsigned short* y;
    if (i < NROWS * EMB / 4) { x = t; y = tb; }
    else { x = s; y = sb; i -= NROWS * EMB / 4; }
    float4 v = ((const float4*)x)[i];
    ushort4 o;
    o.x = f2bf(v.x); o.y = f2bf(v.y); o.z = f2bf(v.z); o.w = f2bf(v.w);
    ((ushort4*)y)[i] = o;
    return;
  }
  const int e = bx - 8192;
  const int z = e >> 8, tt = e & 255;
  const float* Ws[8] = {W0, W1, W2, W3, W4, W5, W6, W7};
  const float* W = Ws[z];
  unsigned short* dst = Wt + ((size_t)z << 20);
  __shared__ unsigned short tile[64][65];
  const int n0 = (tt & 15) * 64, k0 = (tt >> 4) * 64;
#pragma unroll
  for (int i = 0; i < 16; ++i) {
    const int ee = i * 256 + threadIdx.x;
    const int kk = ee >> 6, nn = ee & 63;
    tile[kk][nn] = f2bf(W[(size_t)(k0 + kk) * EMB + n0 + nn]);
  }
  __syncthreads();
#pragma unroll
  for (int i = 0; i < 16; ++i) {
    const int ee = i * 256 + threadIdx.x;
    const int nn = ee >> 6, kk = ee & 63;
    dst[(size_t)(n0 + nn) * EMB + k0 + kk] = tile[kk][nn];
  }
}

// ------- 128x128 GEMM core, BK=64, XOR-swizzled LDS (conflict-free), 32 MFMA/iter -------
// Swizzle folded into GLOBAL source address (LDS dest stays linear for global_load_lds).
__device__ __forceinline__ void gemm_core64(const unsigned short* __restrict__ A,
                                            const unsigned short* __restrict__ Bt,
                                            int m0, int bt0,
                                            unsigned short* As, unsigned short* Bs,
                                            f32x4 (&acc)[4][4]) {
  const int tid = threadIdx.x;
  const int w = tid >> 6, lane = tid & 63;
  const int quad = lane >> 4, l16 = lane & 15;
  const int wm = w & 1, wn = w >> 1;
  const int sw8 = l16 & 7;

  // staging: wave w owns rows [w*32, w*32+32) of both As and Bs; 4 instrs each
  const int srow = lane >> 3, p8 = lane & 7;
  const unsigned short* Ag[4];
  const unsigned short* Bg[4];
#pragma unroll
  for (int i = 0; i < 4; ++i) {
    const int r = w * 32 + i * 8 + srow;
    Ag[i] = A + (size_t)(m0 + r) * EMB + ((p8 ^ (r & 7)) * 8);
    Bg[i] = Bt + (size_t)(bt0 + r) * EMB + ((p8 ^ (r & 7)) * 8);
  }
  unsigned short* AsB[4];
  unsigned short* BsB[4];
#pragma unroll
  for (int i = 0; i < 4; ++i) {
    AsB[i] = As + (w * 32 + i * 8) * 64;
    BsB[i] = Bs + (w * 32 + i * 8) * 64;
  }

  for (int kk = 0; kk < EMB; kk += 64) {
    __syncthreads();
#pragma unroll
    for (int i = 0; i < 4; ++i) {
      async_load16(Ag[i] + kk, AsB[i]);
      async_load16(Bg[i] + kk, BsB[i]);
    }
    __syncthreads();
#pragma unroll
    for (int h = 0; h < 2; ++h) {
      bf16x8 af[4], bfr[4];
#pragma unroll
      for (int im = 0; im < 4; ++im)
        af[im] = *(const bf16x8*)(As + (wm * 64 + im * 16 + l16) * 64 +
                                  (((h * 4 + quad) ^ sw8) * 8));
#pragma unroll
      for (int in = 0; in < 4; ++in)
        bfr[in] = *(const bf16x8*)(Bs + (wn * 64 + in * 16 + l16) * 64 +
                                   (((h * 4 + quad) ^ sw8) * 8));
#pragma unroll
      for (int im = 0; im < 4; ++im)
#pragma unroll
        for (int in = 0; in < 4; ++in)
          acc[im][in] = mfma16(af[im], bfr[in], acc[im][in]);
    }
  }
}

// ---------------- fused QKV projection, fused BY ACTIVATION (R16) ----------------
// Each activation feeds exactly 3 GEMMs: tempb -> {Q_s2t, K_t2s, V_t2s},
// spatb -> {K_s2t, V_s2t, Q_t2s}. One block stages the A-tile ONCE and runs
// 96 MFMA per barrier pair (vs 32) -> the ~900TF barrier-drain ceiling amortizes 3x,
// and A-side fetch drops 3x. LDS = As 16KB + Bs 48KB = 64KB -> 2 blocks/CU.
// grid (16, 32): act = bx>>3, n0 = (bx&7)*128, m0 = by*128. XCD remap: each XCD
// owns a contiguous (act, m-range) chunk -> A-panels L2-resident.
// j=0: Q (pre-scaled 0.125*log2(e)); j=1: K; j=2: V (transposed store, LDS re-gather).
__global__ __launch_bounds__(256, 2) void gemm_qkv(const unsigned short* __restrict__ tempb,
                                                   const unsigned short* __restrict__ spatb,
                                                   const unsigned short* __restrict__ Wt,
                                                   const float* __restrict__ bq0,
                                                   const float* __restrict__ bk0,
                                                   const float* __restrict__ bv0,
                                                   const float* __restrict__ bq1,
                                                   const float* __restrict__ bk1,
                                                   const float* __restrict__ bv1,
                                                   unsigned short* __restrict__ Qb,
                                                   unsigned short* __restrict__ Kb,
                                                   unsigned short* __restrict__ Vtb) {
  __shared__ alignas(16) unsigned short As[128 * 64];       // 16KB
  __shared__ alignas(16) unsigned short Bs[3 * 128 * 64];   // 48KB; also V-scratch
  const size_t DOF = (size_t)NROWS * EMB;

  // XCD-aware bijective remap over 512 blocks: xcd = phys&7 owns 64 consecutive virt.
  const int phys = blockIdx.x + (blockIdx.y << 4);  // gridDim.x == 16
  const int virt = ((phys & 7) << 6) + (phys >> 3); // 0..511
  const int act = virt >> 8;                        // 0: tempb, 1: spatb
  const int rem = virt & 255;
  const int m0 = (rem >> 3) * 128;                  // 32 m-blocks
  const int n0 = (rem & 7) * 128;                   // 8 n-blocks

  const unsigned short* A = act ? spatb : tempb;
  // Wt slot = dir*4 + kind; act0: Q dir0, K dir1, V dir1; act1: Q dir1, K dir0, V dir0.
  const int slot[3] = {act ? 4 : 0, act ? 1 : 5, act ? 2 : 6};
  const float* bias[3];
  bias[0] = act ? bq1 : bq0;
  bias[1] = act ? bk0 : bk1;
  bias[2] = act ? bv0 : bv1;
  unsigned short* Qout = Qb + (act ? DOF : 0);
  unsigned short* Kout = Kb + (act ? 0 : DOF);
  unsigned short* Vout = Vtb + (act ? 0 : DOF);

  const int tid = threadIdx.x;
  const int w = tid >> 6, lane = tid & 63;
  const int quad = lane >> 4, l16 = lane & 15;
  const int wm = w & 1, wn = w >> 1;
  const int sw8 = l16 & 7;

  // staging: wave w owns rows [w*32, w*32+32) of As and each Bs[j]; 16 instrs total
  const int srow = lane >> 3, p8 = lane & 7;
  const unsigned short* Ag[4];
  const unsigned short* Bg[3][4];
  unsigned short* AsB[4];
  unsigned short* BsB[3][4];
#pragma unroll
  for (int i = 0; i < 4; ++i) {
    const int r = w * 32 + i * 8 + srow;
    const int swo = (p8 ^ (r & 7)) * 8;
    Ag[i] = A + (size_t)(m0 + r) * EMB + swo;
    AsB[i] = As + (w * 32 + i * 8) * 64;
#pragma unroll
    for (int j = 0; j < 3; ++j) {
      Bg[j][i] = Wt + ((size_t)slot[j] << 20) + (size_t)(n0 + r) * EMB + swo;
      BsB[j][i] = Bs + j * 8192 + (w * 32 + i * 8) * 64;
    }
  }

  f32x4 acc[3][4][4] = {};
  for (int kk = 0; kk < EMB; kk += 64) {
    __syncthreads();
#pragma unroll
    for (int i = 0; i < 4; ++i) async_load16(Ag[i] + kk, AsB[i]);
#pragma unroll
    for (int j = 0; j < 3; ++j)
#pragma unroll
      for (int i = 0; i < 4; ++i) async_load16(Bg[j][i] + kk, BsB[j][i]);
    __syncthreads();
#pragma unroll
    for (int h = 0; h < 2; ++h) {
      bf16x8 af[4];
#pragma unroll
      for (int im = 0; im < 4; ++im)
        af[im] = *(const bf16x8*)(As + (wm * 64 + im * 16 + l16) * 64 +
                                  (((h * 4 + quad) ^ sw8) * 8));
#pragma unroll
      for (int j = 0; j < 3; ++j) {
        bf16x8 bfr[4];
#pragma unroll
        for (int in = 0; in < 4; ++in)
          bfr[in] = *(const bf16x8*)(Bs + j * 8192 + (wn * 64 + in * 16 + l16) * 64 +
                                     (((h * 4 + quad) ^ sw8) * 8));
#pragma unroll
        for (int im = 0; im < 4; ++im)
#pragma unroll
          for (int in = 0; in < 4; ++in)
            acc[j][im][in] = mfma16(af[im], bfr[in], acc[j][im][in]);
      }
    }
  }

  const int rowb = m0 + wm * 64;
  // ---- Q epilogue (scaled) and K epilogue: plain scatter stores (no LDS) ----
  {
    const float scale = 0.18033688011112042f;  // 0.125 * log2(e)
#pragma unroll
    for (int in = 0; in < 4; ++in) {
      const int col = n0 + wn * 64 + in * 16 + l16;
      const float bq = bias[0][col];
      const float bk = bias[1][col];
#pragma unroll
      for (int im = 0; im < 4; ++im)
#pragma unroll
        for (int r = 0; r < 4; ++r) {
          const int row = rowb + im * 16 + quad * 4 + r;
          Qout[(size_t)row * EMB + col] = f2bf((acc[0][im][in][r] + bq) * scale);
          Kout[(size_t)row * EMB + col] = f2bf(acc[1][im][in][r] + bk);
        }
    }
  }
  // ---- V epilogue: transposed, coalesced via per-wave LDS re-gather ----
  __syncthreads();  // all waves done reading As/Bs fragments
  unsigned short* sc = Bs + w * 4096;  // 8KB per wave (fits: 4*4096 <= 3*8192)
  const int colbase = n0 + wn * 64;    // 64-aligned -> one head per wave
  const int hh = colbase >> 6;
  const int bb = rowb >> 11;
  const int key0 = rowb & 2047;
  const int sw2 = (l16 & 7) << 1;
#pragma unroll
  for (int in = 0; in < 4; ++in) {
    const int drow = in * 16 + l16;
    const float bvv = bias[2][colbase + in * 16 + l16];
#pragma unroll
    for (int im = 0; im < 4; ++im) {
      uint2 pk;
      pk.x = (unsigned int)f2bf(acc[2][im][in][0] + bvv) |
             ((unsigned int)f2bf(acc[2][im][in][1] + bvv) << 16);
      pk.y = (unsigned int)f2bf(acc[2][im][in][2] + bvv) |
             ((unsigned int)f2bf(acc[2][im][in][3] + bvv) << 16);
      const int kb = im * 4 + quad;
      *(uint2*)(sc + drow * 64 + ((kb ^ sw2) << 2)) = pk;
    }
  }
  asm volatile("" ::: "memory");
  unsigned short* Vt = Vout + ((size_t)(bb * 16 + hh) * 64) * SEQ + key0;
  const int rl = lane >> 3;
  const int c = lane & 7;
#pragma unroll
  for (int p = 0; p < 8; ++p) {
    const int d = p * 8 + rl;
    const int kbs = (c * 2) ^ ((d & 7) << 1);
    ushort8 v = *(const ushort8*)(sc + d * 64 + (kbs << 2));
    *(ushort8*)(Vt + (size_t)d * SEQ + c * 8) = v;
  }
}

// ------- output projection GEMM, both dirs: projb (bf16) = acc + bias + resid -------
// grid (16, 32): dir = bx>>3, n0 = (bx&7)*128, m0 = by*128.
__global__ __launch_bounds__(256, 3) void gemm_o(const unsigned short* __restrict__ Ob,
                                                 const unsigned short* __restrict__ Wt,
                                                 const float* __restrict__ bo0,
                                                 const float* __restrict__ bo1,
                                                 const float* __restrict__ temp,
                                                 const float* __restrict__ spat,
                                                 unsigned short* __restrict__ projb) {
  __shared__ alignas(16) unsigned short As[128 * 64];
  __shared__ alignas(16) unsigned short Bs[128 * 64];
  const int dir = blockIdx.x >> 3;
  const int n0 = (blockIdx.x & 7) * 128;
  const size_t dof = (size_t)dir * NROWS * EMB;
  const float* bias = dir ? bo1 : bo0;
  const float* resid = dir ? spat : temp;

  f32x4 acc[4][4] = {};
  gemm_core64(Ob + dof, Wt + ((size_t)(dir * 4 + 3) << 20), blockIdx.y * 128, n0, As, Bs,
              acc);

  const int tid = threadIdx.x;
  const int w = tid >> 6, lane = tid & 63;
  const int quad = lane >> 4, l16 = lane & 15;
  const int wm = w & 1, wn = w >> 1;
  const int rowb = blockIdx.y * 128 + wm * 64;
  unsigned short* outb = projb + dof;
#pragma unroll
  for (int in = 0; in < 4; ++in) {
    const int col = n0 + wn * 64 + in * 16 + l16;
    const float bvv = bias[col];
#pragma unroll
    for (int im = 0; im < 4; ++im)
#pragma unroll
      for (int r = 0; r < 4; ++r) {
        const int row = rowb + im * 16 + quad * 4 + r;
        const size_t off = (size_t)row * EMB + col;
        outb[off] = f2bf(acc[im][in][r] + bvv + resid[off]);
      }
  }
}

// ---------------- flash attention (R11/R14 verified, ~70us): single dispatch ----------
// Register-resident P via kappa-permuted K staging; K+V dbuf (32KB, 4 blocks/CU);
// 2 barriers/tile, counted vmcnt(4); x2-unrolled kt loop; cvt-pk P-pack; XCD remap;
// setprio around MFMA clusters; epilogue scratch aliases Ks.
__global__ __launch_bounds__(256, 4) void flash_attn(const unsigned short* __restrict__ Qall,
                                                     const unsigned short* __restrict__ Kall,
                                                     const unsigned short* __restrict__ Vtall,
                                                     unsigned short* __restrict__ Oall) {
  __shared__ alignas(16) unsigned short Ks[2][64 * 64];  // [buf][row][d]; also epilogue scratch
  __shared__ alignas(16) unsigned short Vs[2][64 * 64];  // [buf][d][key]

  const int tid = threadIdx.x;
  const int w = tid >> 6, lane = tid & 63;
  const int quad = lane >> 4, l16 = lane & 15;
  // XCD-aware bijective remap.
  const int phys = blockIdx.x + (blockIdx.y << 4);  // gridDim.x == 16
  const int xcd = phys & 7, slot = phys >> 3;       // slot in 0..127
  const int bxv = slot & 15;                        // q-block index
  const int byv = (xcd << 3) + (slot >> 4);         // dir*32 + bh
  const int dir = byv >> 5, bh = byv & 31;
  const int b = bh >> 4, h = bh & 15;
  const size_t dof = (size_t)dir * NROWS * EMB;
  const unsigned short* Q = Qall + dof;
  const unsigned short* K = Kall + dof;
  const unsigned short* Vt = Vtall + dof;
  unsigned short* O = Oall + dof;
  const int q0 = bxv * 128 + w * 32;

  bf16x8 qf[2][2];
#pragma unroll
  for (int qh = 0; qh < 2; ++qh) {
    const unsigned short* Qrow = Q + (size_t)(b * SEQ + q0 + qh * 16 + l16) * EMB + h * 64;
    qf[qh][0] = *(const bf16x8*)(Qrow + quad * 8);
    qf[qh][1] = *(const bf16x8*)(Qrow + 32 + quad * 8);
  }

  bf16x8 onesf;
#pragma unroll
  for (int i = 0; i < 8; ++i) onesf[i] = (__bf16)1.0f;

  f32x4 oaccT[2][4] = {};  // [qh][dg]: O^T[d = dg*16+quad*4+r][q = qh*16+l16]
  f32x4 rs[2] = {};        // rowsum per qh (ones-MFMA, col = q)
  const int swz = (l16 & 7) << 1;  // epilogue swizzle
  const int sw8 = l16 & 7;

  // async staging: wave w owns LDS rows [w*16, w*16+16), 2 instrs each (8 rows/instr).
  const int r8 = lane >> 3, p8 = lane & 7;
  // K global rows PERMUTED: LDS row rho = w*16 + r8 (and +8) holds key kappa(rho).
  // kappa(rho): g=rho>>4, q=(rho>>2)&3, r=rho&3  ->  (g>>1)*32 + q*8 + (g&1)*4 + r.
  const int gk0 = ((w >> 1) << 5) + ((r8 >> 2) << 3) + ((w & 1) << 2) + (r8 & 3);
  const int gk1 = gk0 + 16;  // rho+8 flips bit3 of rho -> q += 2 -> key += 16
  const int kr0 = w * 16 + r8;  // d-row index for V staging (unpermuted)
  const int kr1 = kr0 + 8;
  const unsigned short* Ksrc0 = K + (size_t)(b * SEQ + gk0) * EMB + h * 64 + ((p8 ^ r8) * 8);
  const unsigned short* Ksrc1 = K + (size_t)(b * SEQ + gk1) * EMB + h * 64 + ((p8 ^ r8) * 8);
  const unsigned short* Vsrc0 = Vt + ((size_t)bh * 64 + kr0) * SEQ + ((p8 ^ (kr0 & 7)) * 8);
  const unsigned short* Vsrc1 = Vt + ((size_t)bh * 64 + kr1) * SEQ + ((p8 ^ (kr1 & 7)) * 8);
  unsigned short* KsW0 = &Ks[0][0] + (w * 16) * 64;
  unsigned short* KsW1 = &Ks[0][0] + (w * 16 + 8) * 64;
  unsigned short* VsW0 = &Vs[0][0] + (w * 16) * 64;
  unsigned short* VsW1 = &Vs[0][0] + (w * 16 + 8) * 64;

  // prologue: issue tile 0 into buffer 0 (no wait yet; loop's vmcnt covers it)
  async_load16(Ksrc0, KsW0);
  async_load16(Ksrc1, KsW1);
  async_load16(Vsrc0, VsW0);
  async_load16(Vsrc1, VsW1);

  // one k-tile step; KsC/VsC and the prefetch dsts are compile-time per call site
  auto tile_step = [&](int ktn, bool more, const unsigned short* KsC,
                       const unsigned short* VsC, unsigned short* KD0,
                       unsigned short* KD1, unsigned short* VD0, unsigned short* VD1) {
    if (more) {
      async_load16(Ksrc0 + (size_t)ktn * EMB, KD0);
      async_load16(Ksrc1 + (size_t)ktn * EMB, KD1);
      async_load16(Vsrc0 + ktn, VD0);
      async_load16(Vsrc1 + ktn, VD1);
      // wait current tile's 4 loads only; leave next tile's 4 in flight
      asm volatile("s_waitcnt vmcnt(4)" ::: "memory");
    } else {
      asm volatile("s_waitcnt vmcnt(0)" ::: "memory");
    }
    __builtin_amdgcn_s_barrier();  // all waves' current-tile K AND V in LDS
    asm volatile("" ::: "memory");

    // S^T = K @ Q^T; P = exp2 -> bf16 via casts (compiler emits v_cvt_pk_bf16_f32)
    bf16x8 pb[2][2];
    __builtin_amdgcn_s_setprio(1);
#pragma unroll
    for (int g = 0; g < 4; ++g) {
      const int krow = g * 16 + l16;
      bf16x8 kf0 = *(const bf16x8*)(KsC + krow * 64 + ((quad ^ sw8) * 8));
      bf16x8 kf1 = *(const bf16x8*)(KsC + krow * 64 + (((4 + quad) ^ sw8) * 8));
#pragma unroll
      for (int qh = 0; qh < 2; ++qh) {
        f32x4 z = {};
        z = mfma16(kf0, qf[qh][0], z);
        z = mfma16(kf1, qf[qh][1], z);
        const int s = g >> 1, o4 = (g & 1) * 4;
        pb[qh][s][o4 + 0] = (__bf16)__builtin_amdgcn_exp2f(z[0]);
        pb[qh][s][o4 + 1] = (__bf16)__builtin_amdgcn_exp2f(z[1]);
        pb[qh][s][o4 + 2] = (__bf16)__builtin_amdgcn_exp2f(z[2]);
        pb[qh][s][o4 + 3] = (__bf16)__builtin_amdgcn_exp2f(z[3]);
      }
    }
    __builtin_amdgcn_s_setprio(0);
    // Rowsum via ones-MFMA (key-order-independent; kappa permutation is free).
#pragma unroll
    for (int qh = 0; qh < 2; ++qh)
      rs[qh] = mfma16(onesf, pb[qh][1], mfma16(onesf, pb[qh][0], rs[qh]));

    // O^T += V^T @ P^T (V fragments shared across q-halves)
    __builtin_amdgcn_s_setprio(1);
#pragma unroll
    for (int dg = 0; dg < 4; ++dg) {
      const int dd = dg * 16 + l16;
      bf16x8 v0 = *(const bf16x8*)(VsC + dd * 64 + ((quad ^ sw8) * 8));
      bf16x8 v1 = *(const bf16x8*)(VsC + dd * 64 + (((4 + quad) ^ sw8) * 8));
#pragma unroll
      for (int qh = 0; qh < 2; ++qh) {
        oaccT[qh][dg] = mfma16(v0, pb[qh][0], oaccT[qh][dg]);
        oaccT[qh][dg] = mfma16(v1, pb[qh][1], oaccT[qh][dg]);
      }
    }
    __builtin_amdgcn_s_setprio(0);
    asm volatile("" ::: "memory");  // keep LDS reads above the trailing barrier
    __builtin_amdgcn_s_barrier();   // all waves done with this buffer; safe to re-stage
  };

  // kt loop unrolled x2: buffer bases compile-time (buf1 = +4096 shorts = +8192B imm)
  for (int kt = 0; kt < SEQ; kt += 128) {
    // tile kt in buf0; prefetch kt+64 -> buf1 (kt+64 <= 1984 < SEQ always)
    tile_step(kt + 64, true, &Ks[0][0], &Vs[0][0],
              KsW0 + 4096, KsW1 + 4096, VsW0 + 4096, VsW1 + 4096);
    // tile kt+64 in buf1; prefetch kt+128 -> buf0 unless done
    tile_step(kt + 128, kt + 128 < SEQ, &Ks[1][0], &Vs[1][0],
              KsW0, KsW1, VsW0, VsW1);
  }

  // epilogue: per q-half, transpose O^T back through per-wave scratch (ALIASES Ks --
  // dead after the loop; last trailing barrier guarantees all LDS reads completed).
  unsigned short* pw = &Ks[0][0] + w * 1024;  // 2KB per wave, 8KB total (fits in Ks[0])
#pragma unroll
  for (int qh = 0; qh < 2; ++qh) {
    const float inv = 1.0f / rs[qh][0];
#pragma unroll
    for (int dg = 0; dg < 4; ++dg) {
      uint2 pkk;
      pkk.x = (unsigned int)f2bf(oaccT[qh][dg][0] * inv) |
              ((unsigned int)f2bf(oaccT[qh][dg][1] * inv) << 16);
      pkk.y = (unsigned int)f2bf(oaccT[qh][dg][2] * inv) |
              ((unsigned int)f2bf(oaccT[qh][dg][3] * inv) << 16);
      const int kb = 4 * dg + quad;
      *(uint2*)(pw + l16 * 64 + ((kb ^ swz) << 2)) = pkk;
    }
    asm volatile("" ::: "memory");
    const int qq = lane >> 2, cc = lane & 3;
    const int swq = (qq & 7) << 1;
    ushort8 r0 = *(const ushort8*)(pw + qq * 64 + (((4 * cc) ^ swq) << 2));
    ushort8 r1 = *(const ushort8*)(pw + qq * 64 + (((4 * cc + 2) ^ swq) << 2));
    unsigned short* Orow = O + (size_t)(b * SEQ + q0 + qh * 16 + qq) * EMB + h * 64 + cc * 16;
    *(ushort8*)(Orow) = r0;
    *(ushort8*)(Orow + 8) = r1;
    asm volatile("" ::: "memory");
  }
}

// ---------------- layernorm: one block per row, both dirs; bf16 input, fp32 math ----------------
__global__ __launch_bounds__(256) void ln_k(const unsigned short* __restrict__ X,
                                            const float* __restrict__ g,
                                            const float* __restrict__ bb,
                                            float* __restrict__ out) {
  const int row = blockIdx.x;
  const int tid = threadIdx.x;
  const ushort4 hv = ((const ushort4*)(X + (size_t)row * EMB))[tid];
  float4 v;
  v.x = bf2f(hv.x); v.y = bf2f(hv.y); v.z = bf2f(hv.z); v.w = bf2f(hv.w);
  float s = v.x + v.y + v.z + v.w;
  float s2 = v.x * v.x + v.y * v.y + v.z * v.z + v.w * v.w;
#pragma unroll
  for (int o = 32; o > 0; o >>= 1) {
    s += __shfl_down(s, o);
    s2 += __shfl_down(s2, o);
  }
  __shared__ float ws[4], ws2[4];
  if ((tid & 63) == 0) { ws[tid >> 6] = s; ws2[tid >> 6] = s2; }
  __syncthreads();
  const float S = ws[0] + ws[1] + ws[2] + ws[3];
  const float S2 = ws2[0] + ws2[1] + ws2[2] + ws2[3];
  const float mu = S * (1.f / EMB);
  const float inv = rsqrtf(S2 * (1.f / EMB) - mu * mu + 1e-5f);
  const float4 gv = ((const float4*)g)[tid];
  const float4 bv = ((const float4*)bb)[tid];
  float4 o4;
  o4.x = (v.x - mu) * inv * gv.x + bv.x;
  o4.y = (v.y - mu) * inv * gv.y + bv.y;
  o4.z = (v.z - mu) * inv * gv.z + bv.z;
  o4.w = (v.w - mu) * inv * gv.w + bv.w;
  ((float4*)(out + (size_t)row * EMB))[tid] = o4;
}

extern "C" void kernel_launch(void* const* d_in, const int* in_sizes, int n_in,
                              void* d_out, int out_size, void* d_ws, size_t ws_size,
                              hipStream_t stream) {
  const float* temp = (const float*)d_in[0];
  const float* spat = (const float*)d_in[1];
  // t2s weights: d_in[2..9], s2t weights: d_in[10..17]
  const float* lng = (const float*)d_in[18];
  const float* lnb = (const float*)d_in[19];
  float* out = (float*)d_out;

  char* base = (char*)d_ws;
  unsigned short* tempb = (unsigned short*)(base + ((size_t)0 << 20));
  unsigned short* spatb = (unsigned short*)(base + ((size_t)8 << 20));
  unsigned short* Wt = (unsigned short*)(base + ((size_t)16 << 20));   // 8 x 1024x1024 bf16
  unsigned short* Qb = (unsigned short*)(base + ((size_t)32 << 20));   // 2 dirs
  unsigned short* Kb = (unsigned short*)(base + ((size_t)48 << 20));
  unsigned short* Vtb = (unsigned short*)(base + ((size_t)64 << 20));
  unsigned short* Ob = (unsigned short*)(base + ((size_t)80 << 20));
  unsigned short* projb = (unsigned short*)(base + ((size_t)32 << 20));  // aliases Qb (dead after flash)

  // Wt order: dir0 = s2t {Wq,Wk,Wv,Wo} = d_in[10,12,14,16]; dir1 = t2s = d_in[2,4,6,8]
  prep<<<8192 + 2048, 256, 0, stream>>>(
      temp, spat, tempb, spatb, (const float*)d_in[10], (const float*)d_in[12],
      (const float*)d_in[14], (const float*)d_in[16], (const float*)d_in[2],
      (const float*)d_in[4], (const float*)d_in[6], (const float*)d_in[8], Wt);
  gemm_qkv<<<dim3(16, 32), 256, 0, stream>>>(
      tempb, spatb, Wt, (const float*)d_in[11], (const float*)d_in[13],
      (const float*)d_in[15], (const float*)d_in[3], (const float*)d_in[5],
      (const float*)d_in[7], Qb, Kb, Vtb);
  flash_attn<<<dim3(16, 64), 256, 0, stream>>>(Qb, Kb, Vtb, Ob);
  gemm_o<<<dim3(16, 32), 256, 0, stream>>>(Ob, Wt, (const float*)d_in[17],
                                           (const float*)d_in[9], temp, spat, projb);
  ln_k<<<2 * NROWS, 256, 0, stream>>>(projb, lng, lnb, out);
}

// Round 14
// 296.307 us; speedup vs baseline: 1.0924x; 1.0924x over previous
//
#include <hip/hip_runtime.h>
#include <stdint.h>

#define SEQ 2048
#define EMB 1024
#define NROWS 4096  // 2 batches * 2048

typedef __bf16 bf16x8 __attribute__((ext_vector_type(8)));
typedef float f32x4 __attribute__((ext_vector_type(4)));
typedef unsigned short ushort8 __attribute__((ext_vector_type(8)));

__device__ __forceinline__ unsigned short f2bf(float f) {
  unsigned int u = __float_as_uint(f);
  u += 0x7fffu + ((u >> 16) & 1u);
  return (unsigned short)(u >> 16);
}

__device__ __forceinline__ float bf2f(unsigned short h) {
  return __uint_as_float((unsigned int)h << 16);
}

__device__ __forceinline__ f32x4 mfma16(bf16x8 a, bf16x8 b, f32x4 c) {
  return __builtin_amdgcn_mfma_f32_16x16x32_bf16(a, b, c, 0, 0, 0);
}

// async global->LDS, 16B per lane; lds dest = wave-uniform base + lane*16
__device__ __forceinline__ void async_load16(const void* g, void* l) {
  auto gp = reinterpret_cast<__attribute__((address_space(1))) void*>(
      reinterpret_cast<uintptr_t>(g));
  auto lp = reinterpret_cast<__attribute__((address_space(3))) void*>(
      reinterpret_cast<uintptr_t>(l));
  __builtin_amdgcn_global_load_lds(gp, lp, 16, 0, 0);
}

// ------- prep: fp32->bf16 convert of both inputs + 8x weight transpose, ONE launch -------
// blocks [0, 8192): cvt (4 float4 per thread-block row); blocks [8192, 10240): wtrans.
__global__ __launch_bounds__(256) void prep(const float* __restrict__ t,
                                            const float* __restrict__ s,
                                            unsigned short* __restrict__ tb,
                                            unsigned short* __restrict__ sb,
                                            const float* __restrict__ W0,
                                            const float* __restrict__ W1,
                                            const float* __restrict__ W2,
                                            const float* __restrict__ W3,
                                            const float* __restrict__ W4,
                                            const float* __restrict__ W5,
                                            const float* __restrict__ W6,
                                            const float* __restrict__ W7,
                                            unsigned short* __restrict__ Wt) {
  const int bx = blockIdx.x;
  if (bx < 8192) {
    int i = bx * 256 + threadIdx.x;
    const float* x; unsigned short* y;
    if (i < NROWS * EMB / 4) { x = t; y = tb; }
    else { x = s; y = sb; i -= NROWS * EMB / 4; }
    float4 v = ((const float4*)x)[i];
    ushort4 o;
    o.x = f2bf(v.x); o.y = f2bf(v.y); o.z = f2bf(v.z); o.w = f2bf(v.w);
    ((ushort4*)y)[i] = o;
    return;
  }
  const int e = bx - 8192;
  const int z = e >> 8, tt = e & 255;
  const float* Ws[8] = {W0, W1, W2, W3, W4, W5, W6, W7};
  const float* W = Ws[z];
  unsigned short* dst = Wt + ((size_t)z << 20);
  __shared__ unsigned short tile[64][65];
  const int n0 = (tt & 15) * 64, k0 = (tt >> 4) * 64;
#pragma unroll
  for (int i = 0; i < 16; ++i) {
    const int ee = i * 256 + threadIdx.x;
    const int kk = ee >> 6, nn = ee & 63;
    tile[kk][nn] = f2bf(W[(size_t)(k0 + kk) * EMB + n0 + nn]);
  }
  __syncthreads();
#pragma unroll
  for (int i = 0; i < 16; ++i) {
    const int ee = i * 256 + threadIdx.x;
    const int nn = ee >> 6, kk = ee & 63;
    dst[(size_t)(n0 + nn) * EMB + k0 + kk] = tile[kk][nn];
  }
}

// ------- 128x128 GEMM core, BK=64, XOR-swizzled LDS (conflict-free), 32 MFMA/iter -------
// Swizzle folded into GLOBAL source address (LDS dest stays linear for global_load_lds).
__device__ __forceinline__ void gemm_core64(const unsigned short* __restrict__ A,
                                            const unsigned short* __restrict__ Bt,
                                            int m0, int bt0,
                                            unsigned short* As, unsigned short* Bs,
                                            f32x4 (&acc)[4][4]) {
  const int tid = threadIdx.x;
  const int w = tid >> 6, lane = tid & 63;
  const int quad = lane >> 4, l16 = lane & 15;
  const int wm = w & 1, wn = w >> 1;
  const int sw8 = l16 & 7;

  // staging: wave w owns rows [w*32, w*32+32) of both As and Bs; 4 instrs each
  const int srow = lane >> 3, p8 = lane & 7;
  const unsigned short* Ag[4];
  const unsigned short* Bg[4];
#pragma unroll
  for (int i = 0; i < 4; ++i) {
    const int r = w * 32 + i * 8 + srow;
    Ag[i] = A + (size_t)(m0 + r) * EMB + ((p8 ^ (r & 7)) * 8);
    Bg[i] = Bt + (size_t)(bt0 + r) * EMB + ((p8 ^ (r & 7)) * 8);
  }
  unsigned short* AsB[4];
  unsigned short* BsB[4];
#pragma unroll
  for (int i = 0; i < 4; ++i) {
    AsB[i] = As + (w * 32 + i * 8) * 64;
    BsB[i] = Bs + (w * 32 + i * 8) * 64;
  }

  for (int kk = 0; kk < EMB; kk += 64) {
    __syncthreads();
#pragma unroll
    for (int i = 0; i < 4; ++i) {
      async_load16(Ag[i] + kk, AsB[i]);
      async_load16(Bg[i] + kk, BsB[i]);
    }
    __syncthreads();
#pragma unroll
    for (int h = 0; h < 2; ++h) {
      bf16x8 af[4], bfr[4];
#pragma unroll
      for (int im = 0; im < 4; ++im)
        af[im] = *(const bf16x8*)(As + (wm * 64 + im * 16 + l16) * 64 +
                                  (((h * 4 + quad) ^ sw8) * 8));
#pragma unroll
      for (int in = 0; in < 4; ++in)
        bfr[in] = *(const bf16x8*)(Bs + (wn * 64 + in * 16 + l16) * 64 +
                                   (((h * 4 + quad) ^ sw8) * 8));
#pragma unroll
      for (int im = 0; im < 4; ++im)
#pragma unroll
        for (int in = 0; in < 4; ++in)
          acc[im][in] = mfma16(af[im], bfr[in], acc[im][in]);
    }
  }
}

// ---------------- fused Q|K|V projection GEMM, BOTH directions (R14 config: 890 TF) -------
// grid (48, 32): idx = bx>>3 in 0..5 = dir*3 + {Q,K,V}; n0 = (bx&7)*128; m0 = by*128.
// dir0 = s2t (q from temp, kv from spat), dir1 = t2s.
// Q pre-scaled by 0.125*log2(e). V written TRANSPOSED into Vt[bh][d][key], coalesced
// via per-wave LDS re-gather.
__global__ __launch_bounds__(256, 3) void gemm_qkv(const unsigned short* __restrict__ tempb,
                                                   const unsigned short* __restrict__ spatb,
                                                   const unsigned short* __restrict__ Wt,
                                                   const float* __restrict__ bq0,
                                                   const float* __restrict__ bk0,
                                                   const float* __restrict__ bv0,
                                                   const float* __restrict__ bq1,
                                                   const float* __restrict__ bk1,
                                                   const float* __restrict__ bv1,
                                                   unsigned short* __restrict__ Qb,
                                                   unsigned short* __restrict__ Kb,
                                                   unsigned short* __restrict__ Vtb) {
  __shared__ alignas(16) unsigned short As[128 * 64];
  __shared__ alignas(16) unsigned short Bs[128 * 64];
  const int idx = blockIdx.x >> 3;
  const int dir = idx / 3, kind = idx - dir * 3;
  const int n0 = (blockIdx.x & 7) * 128;
  const unsigned short* A =
      (dir == 0) ? (kind == 0 ? tempb : spatb) : (kind == 0 ? spatb : tempb);
  const float* bias = (dir == 0) ? (kind == 0 ? bq0 : (kind == 1 ? bk0 : bv0))
                                 : (kind == 0 ? bq1 : (kind == 1 ? bk1 : bv1));

  f32x4 acc[4][4] = {};
  gemm_core64(A, Wt + ((size_t)(dir * 4 + kind) << 20), blockIdx.y * 128, n0, As, Bs, acc);

  const int tid = threadIdx.x;
  const int w = tid >> 6, lane = tid & 63;
  const int quad = lane >> 4, l16 = lane & 15;
  const int wm = w & 1, wn = w >> 1;
  const int rowb = blockIdx.y * 128 + wm * 64;
  const size_t dof = (size_t)dir * NROWS * EMB;

  if (kind == 2) {
    // V transposed store, coalesced: pack -> per-wave LDS scratch (XOR-swizzled) ->
    // re-gather -> 128B-contiguous ushort8 stores.
    __syncthreads();  // all waves done reading As/Bs fragments from the K-loop
    unsigned short* sc = (w < 2 ? As : Bs) + (w & 1) * 4096;  // 8KB per wave
    const int colbase = n0 + wn * 64;  // 64-aligned -> single head per wave
    const int hh = colbase >> 6;
    const int bb = rowb >> 11;
    const int key0 = rowb & 2047;
    const int sw2 = (l16 & 7) << 1;
#pragma unroll
    for (int in = 0; in < 4; ++in) {
      const int drow = in * 16 + l16;
      const float bvv = bias[colbase + in * 16 + l16];
#pragma unroll
      for (int im = 0; im < 4; ++im) {
        uint2 pk;
        pk.x = (unsigned int)f2bf(acc[im][in][0] + bvv) |
               ((unsigned int)f2bf(acc[im][in][1] + bvv) << 16);
        pk.y = (unsigned int)f2bf(acc[im][in][2] + bvv) |
               ((unsigned int)f2bf(acc[im][in][3] + bvv) << 16);
        const int kb = im * 4 + quad;
        *(uint2*)(sc + drow * 64 + ((kb ^ sw2) << 2)) = pk;
      }
    }
    asm volatile("" ::: "memory");
    unsigned short* Vt = Vtb + dof + ((size_t)(bb * 16 + hh) * 64) * SEQ + key0;
    const int rl = lane >> 3;
    const int c = lane & 7;
#pragma unroll
    for (int p = 0; p < 8; ++p) {
      const int d = p * 8 + rl;
      const int kbs = (c * 2) ^ ((d & 7) << 1);
      ushort8 v = *(const ushort8*)(sc + d * 64 + (kbs << 2));
      *(ushort8*)(Vt + (size_t)d * SEQ + c * 8) = v;
    }
  } else {
    unsigned short* out = ((kind == 0) ? Qb : Kb) + dof;
    const float scale = (kind == 0) ? 0.18033688011112042f : 1.0f;
#pragma unroll
    for (int in = 0; in < 4; ++in) {
      const int col = n0 + wn * 64 + in * 16 + l16;
      const float bvv = bias[col];
#pragma unroll
      for (int im = 0; im < 4; ++im)
#pragma unroll
        for (int r = 0; r < 4; ++r) {
          const int row = rowb + im * 16 + quad * 4 + r;
          out[(size_t)row * EMB + col] = f2bf((acc[im][in][r] + bvv) * scale);
        }
    }
  }
}

// ------- output projection GEMM, both dirs: projb (bf16) = acc + bias + resid -------
// grid (16, 32): dir = bx>>3, n0 = (bx&7)*128, m0 = by*128.
__global__ __launch_bounds__(256, 3) void gemm_o(const unsigned short* __restrict__ Ob,
                                                 const unsigned short* __restrict__ Wt,
                                                 const float* __restrict__ bo0,
                                                 const float* __restrict__ bo1,
                                                 const float* __restrict__ temp,
                                                 const float* __restrict__ spat,
                                                 unsigned short* __restrict__ projb) {
  __shared__ alignas(16) unsigned short As[128 * 64];
  __shared__ alignas(16) unsigned short Bs[128 * 64];
  const int dir = blockIdx.x >> 3;
  const int n0 = (blockIdx.x & 7) * 128;
  const size_t dof = (size_t)dir * NROWS * EMB;
  const float* bias = dir ? bo1 : bo0;
  const float* resid = dir ? spat : temp;

  f32x4 acc[4][4] = {};
  gemm_core64(Ob + dof, Wt + ((size_t)(dir * 4 + 3) << 20), blockIdx.y * 128, n0, As, Bs,
              acc);

  const int tid = threadIdx.x;
  const int w = tid >> 6, lane = tid & 63;
  const int quad = lane >> 4, l16 = lane & 15;
  const int wm = w & 1, wn = w >> 1;
  const int rowb = blockIdx.y * 128 + wm * 64;
  unsigned short* outb = projb + dof;
#pragma unroll
  for (int in = 0; in < 4; ++in) {
    const int col = n0 + wn * 64 + in * 16 + l16;
    const float bvv = bias[col];
#pragma unroll
    for (int im = 0; im < 4; ++im)
#pragma unroll
      for (int r = 0; r < 4; ++r) {
        const int row = rowb + im * 16 + quad * 4 + r;
        const size_t off = (size_t)row * EMB + col;
        outb[off] = f2bf(acc[im][in][r] + bvv + resid[off]);
      }
  }
}

// ---------------- flash attention (R11/R14 verified, ~70us): single dispatch ----------
// Register-resident P via kappa-permuted K staging; K+V dbuf (32KB, 4 blocks/CU);
// 2 barriers/tile, counted vmcnt(4); x2-unrolled kt loop; cvt-pk P-pack; XCD remap;
// setprio around MFMA clusters; epilogue scratch aliases Ks.
__global__ __launch_bounds__(256, 4) void flash_attn(const unsigned short* __restrict__ Qall,
                                                     const unsigned short* __restrict__ Kall,
                                                     const unsigned short* __restrict__ Vtall,
                                                     unsigned short* __restrict__ Oall) {
  __shared__ alignas(16) unsigned short Ks[2][64 * 64];  // [buf][row][d]; also epilogue scratch
  __shared__ alignas(16) unsigned short Vs[2][64 * 64];  // [buf][d][key]

  const int tid = threadIdx.x;
  const int w = tid >> 6, lane = tid & 63;
  const int quad = lane >> 4, l16 = lane & 15;
  // XCD-aware bijective remap.
  const int phys = blockIdx.x + (blockIdx.y << 4);  // gridDim.x == 16
  const int xcd = phys & 7, slot = phys >> 3;       // slot in 0..127
  const int bxv = slot & 15;                        // q-block index
  const int byv = (xcd << 3) + (slot >> 4);         // dir*32 + bh
  const int dir = byv >> 5, bh = byv & 31;
  const int b = bh >> 4, h = bh & 15;
  const size_t dof = (size_t)dir * NROWS * EMB;
  const unsigned short* Q = Qall + dof;
  const unsigned short* K = Kall + dof;
  const unsigned short* Vt = Vtall + dof;
  unsigned short* O = Oall + dof;
  const int q0 = bxv * 128 + w * 32;

  bf16x8 qf[2][2];
#pragma unroll
  for (int qh = 0; qh < 2; ++qh) {
    const unsigned short* Qrow = Q + (size_t)(b * SEQ + q0 + qh * 16 + l16) * EMB + h * 64;
    qf[qh][0] = *(const bf16x8*)(Qrow + quad * 8);
    qf[qh][1] = *(const bf16x8*)(Qrow + 32 + quad * 8);
  }

  bf16x8 onesf;
#pragma unroll
  for (int i = 0; i < 8; ++i) onesf[i] = (__bf16)1.0f;

  f32x4 oaccT[2][4] = {};  // [qh][dg]: O^T[d = dg*16+quad*4+r][q = qh*16+l16]
  f32x4 rs[2] = {};        // rowsum per qh (ones-MFMA, col = q)
  const int swz = (l16 & 7) << 1;  // epilogue swizzle
  const int sw8 = l16 & 7;

  // async staging: wave w owns LDS rows [w*16, w*16+16), 2 instrs each (8 rows/instr).
  const int r8 = lane >> 3, p8 = lane & 7;
  // K global rows PERMUTED: LDS row rho = w*16 + r8 (and +8) holds key kappa(rho).
  // kappa(rho): g=rho>>4, q=(rho>>2)&3, r=rho&3  ->  (g>>1)*32 + q*8 + (g&1)*4 + r.
  const int gk0 = ((w >> 1) << 5) + ((r8 >> 2) << 3) + ((w & 1) << 2) + (r8 & 3);
  const int gk1 = gk0 + 16;  // rho+8 flips bit3 of rho -> q += 2 -> key += 16
  const int kr0 = w * 16 + r8;  // d-row index for V staging (unpermuted)
  const int kr1 = kr0 + 8;
  const unsigned short* Ksrc0 = K + (size_t)(b * SEQ + gk0) * EMB + h * 64 + ((p8 ^ r8) * 8);
  const unsigned short* Ksrc1 = K + (size_t)(b * SEQ + gk1) * EMB + h * 64 + ((p8 ^ r8) * 8);
  const unsigned short* Vsrc0 = Vt + ((size_t)bh * 64 + kr0) * SEQ + ((p8 ^ (kr0 & 7)) * 8);
  const unsigned short* Vsrc1 = Vt + ((size_t)bh * 64 + kr1) * SEQ + ((p8 ^ (kr1 & 7)) * 8);
  unsigned short* KsW0 = &Ks[0][0] + (w * 16) * 64;
  unsigned short* KsW1 = &Ks[0][0] + (w * 16 + 8) * 64;
  unsigned short* VsW0 = &Vs[0][0] + (w * 16) * 64;
  unsigned short* VsW1 = &Vs[0][0] + (w * 16 + 8) * 64;

  // prologue: issue tile 0 into buffer 0 (no wait yet; loop's vmcnt covers it)
  async_load16(Ksrc0, KsW0);
  async_load16(Ksrc1, KsW1);
  async_load16(Vsrc0, VsW0);
  async_load16(Vsrc1, VsW1);

  // one k-tile step; KsC/VsC and the prefetch dsts are compile-time per call site
  auto tile_step = [&](int ktn, bool more, const unsigned short* KsC,
                       const unsigned short* VsC, unsigned short* KD0,
                       unsigned short* KD1, unsigned short* VD0, unsigned short* VD1) {
    if (more) {
      async_load16(Ksrc0 + (size_t)ktn * EMB, KD0);
      async_load16(Ksrc1 + (size_t)ktn * EMB, KD1);
      async_load16(Vsrc0 + ktn, VD0);
      async_load16(Vsrc1 + ktn, VD1);
      // wait current tile's 4 loads only; leave next tile's 4 in flight
      asm volatile("s_waitcnt vmcnt(4)" ::: "memory");
    } else {
      asm volatile("s_waitcnt vmcnt(0)" ::: "memory");
    }
    __builtin_amdgcn_s_barrier();  // all waves' current-tile K AND V in LDS
    asm volatile("" ::: "memory");

    // S^T = K @ Q^T; P = exp2 -> bf16 via casts (compiler emits v_cvt_pk_bf16_f32)
    bf16x8 pb[2][2];
    __builtin_amdgcn_s_setprio(1);
#pragma unroll
    for (int g = 0; g < 4; ++g) {
      const int krow = g * 16 + l16;
      bf16x8 kf0 = *(const bf16x8*)(KsC + krow * 64 + ((quad ^ sw8) * 8));
      bf16x8 kf1 = *(const bf16x8*)(KsC + krow * 64 + (((4 + quad) ^ sw8) * 8));
#pragma unroll
      for (int qh = 0; qh < 2; ++qh) {
        f32x4 z = {};
        z = mfma16(kf0, qf[qh][0], z);
        z = mfma16(kf1, qf[qh][1], z);
        const int s = g >> 1, o4 = (g & 1) * 4;
        pb[qh][s][o4 + 0] = (__bf16)__builtin_amdgcn_exp2f(z[0]);
        pb[qh][s][o4 + 1] = (__bf16)__builtin_amdgcn_exp2f(z[1]);
        pb[qh][s][o4 + 2] = (__bf16)__builtin_amdgcn_exp2f(z[2]);
        pb[qh][s][o4 + 3] = (__bf16)__builtin_amdgcn_exp2f(z[3]);
      }
    }
    __builtin_amdgcn_s_setprio(0);
    // Rowsum via ones-MFMA (key-order-independent; kappa permutation is free).
#pragma unroll
    for (int qh = 0; qh < 2; ++qh)
      rs[qh] = mfma16(onesf, pb[qh][1], mfma16(onesf, pb[qh][0], rs[qh]));

    // O^T += V^T @ P^T (V fragments shared across q-halves)
    __builtin_amdgcn_s_setprio(1);
#pragma unroll
    for (int dg = 0; dg < 4; ++dg) {
      const int dd = dg * 16 + l16;
      bf16x8 v0 = *(const bf16x8*)(VsC + dd * 64 + ((quad ^ sw8) * 8));
      bf16x8 v1 = *(const bf16x8*)(VsC + dd * 64 + (((4 + quad) ^ sw8) * 8));
#pragma unroll
      for (int qh = 0; qh < 2; ++qh) {
        oaccT[qh][dg] = mfma16(v0, pb[qh][0], oaccT[qh][dg]);
        oaccT[qh][dg] = mfma16(v1, pb[qh][1], oaccT[qh][dg]);
      }
    }
    __builtin_amdgcn_s_setprio(0);
    asm volatile("" ::: "memory");  // keep LDS reads above the trailing barrier
    __builtin_amdgcn_s_barrier();   // all waves done with this buffer; safe to re-stage
  };

  // kt loop unrolled x2: buffer bases compile-time (buf1 = +4096 shorts = +8192B imm)
  for (int kt = 0; kt < SEQ; kt += 128) {
    // tile kt in buf0; prefetch kt+64 -> buf1 (kt+64 <= 1984 < SEQ always)
    tile_step(kt + 64, true, &Ks[0][0], &Vs[0][0],
              KsW0 + 4096, KsW1 + 4096, VsW0 + 4096, VsW1 + 4096);
    // tile kt+64 in buf1; prefetch kt+128 -> buf0 unless done
    tile_step(kt + 128, kt + 128 < SEQ, &Ks[1][0], &Vs[1][0],
              KsW0, KsW1, VsW0, VsW1);
  }

  // epilogue: per q-half, transpose O^T back through per-wave scratch (ALIASES Ks --
  // dead after the loop; last trailing barrier guarantees all LDS reads completed).
  unsigned short* pw = &Ks[0][0] + w * 1024;  // 2KB per wave, 8KB total (fits in Ks[0])
#pragma unroll
  for (int qh = 0; qh < 2; ++qh) {
    const float inv = 1.0f / rs[qh][0];
#pragma unroll
    for (int dg = 0; dg < 4; ++dg) {
      uint2 pkk;
      pkk.x = (unsigned int)f2bf(oaccT[qh][dg][0] * inv) |
              ((unsigned int)f2bf(oaccT[qh][dg][1] * inv) << 16);
      pkk.y = (unsigned int)f2bf(oaccT[qh][dg][2] * inv) |
              ((unsigned int)f2bf(oaccT[qh][dg][3] * inv) << 16);
      const int kb = 4 * dg + quad;
      *(uint2*)(pw + l16 * 64 + ((kb ^ swz) << 2)) = pkk;
    }
    asm volatile("" ::: "memory");
    const int qq = lane >> 2, cc = lane & 3;
    const int swq = (qq & 7) << 1;
    ushort8 r0 = *(const ushort8*)(pw + qq * 64 + (((4 * cc) ^ swq) << 2));
    ushort8 r1 = *(const ushort8*)(pw + qq * 64 + (((4 * cc + 2) ^ swq) << 2));
    unsigned short* Orow = O + (size_t)(b * SEQ + q0 + qh * 16 + qq) * EMB + h * 64 + cc * 16;
    *(ushort8*)(Orow) = r0;
    *(ushort8*)(Orow + 8) = r1;
    asm volatile("" ::: "memory");
  }
}

// ---------------- layernorm: one block per row, both dirs; bf16 input, fp32 math ----------------
__global__ __launch_bounds__(256) void ln_k(const unsigned short* __restrict__ X,
                                            const float* __restrict__ g,
                                            const float* __restrict__ bb,
                                            float* __restrict__ out) {
  const int row = blockIdx.x;
  const int tid = threadIdx.x;
  const ushort4 hv = ((const ushort4*)(X + (size_t)row * EMB))[tid];
  float4 v;
  v.x = bf2f(hv.x); v.y = bf2f(hv.y); v.z = bf2f(hv.z); v.w = bf2f(hv.w);
  float s = v.x + v.y + v.z + v.w;
  float s2 = v.x * v.x + v.y * v.y + v.z * v.z + v.w * v.w;
#pragma unroll
  for (int o = 32; o > 0; o >>= 1) {
    s += __shfl_down(s, o);
    s2 += __shfl_down(s2, o);
  }
  __shared__ float ws[4], ws2[4];
  if ((tid & 63) == 0) { ws[tid >> 6] = s; ws2[tid >> 6] = s2; }
  __syncthreads();
  const float S = ws[0] + ws[1] + ws[2] + ws[3];
  const float S2 = ws2[0] + ws2[1] + ws2[2] + ws2[3];
  const float mu = S * (1.f / EMB);
  const float inv = rsqrtf(S2 * (1.f / EMB) - mu * mu + 1e-5f);
  const float4 gv = ((const float4*)g)[tid];
  const float4 bv = ((const float4*)bb)[tid];
  float4 o4;
  o4.x = (v.x - mu) * inv * gv.x + bv.x;
  o4.y = (v.y - mu) * inv * gv.y + bv.y;
  o4.z = (v.z - mu) * inv * gv.z + bv.z;
  o4.w = (v.w - mu) * inv * gv.w + bv.w;
  ((float4*)(out + (size_t)row * EMB))[tid] = o4;
}

extern "C" void kernel_launch(void* const* d_in, const int* in_sizes, int n_in,
                              void* d_out, int out_size, void* d_ws, size_t ws_size,
                              hipStream_t stream) {
  const float* temp = (const float*)d_in[0];
  const float* spat = (const float*)d_in[1];
  // t2s weights: d_in[2..9], s2t weights: d_in[10..17]
  const float* lng = (const float*)d_in[18];
  const float* lnb = (const float*)d_in[19];
  float* out = (float*)d_out;

  char* base = (char*)d_ws;
  unsigned short* tempb = (unsigned short*)(base + ((size_t)0 << 20));
  unsigned short* spatb = (unsigned short*)(base + ((size_t)8 << 20));
  unsigned short* Wt = (unsigned short*)(base + ((size_t)16 << 20));   // 8 x 1024x1024 bf16
  unsigned short* Qb = (unsigned short*)(base + ((size_t)32 << 20));   // 2 dirs
  unsigned short* Kb = (unsigned short*)(base + ((size_t)48 << 20));
  unsigned short* Vtb = (unsigned short*)(base + ((size_t)64 << 20));
  unsigned short* Ob = (unsigned short*)(base + ((size_t)80 << 20));
  unsigned short* projb = (unsigned short*)(base + ((size_t)32 << 20));  // aliases Qb (dead after flash)

  // Wt order: dir0 = s2t {Wq,Wk,Wv,Wo} = d_in[10,12,14,16]; dir1 = t2s = d_in[2,4,6,8]
  prep<<<8192 + 2048, 256, 0, stream>>>(
      temp, spat, tempb, spatb, (const float*)d_in[10], (const float*)d_in[12],
      (const float*)d_in[14], (const float*)d_in[16], (const float*)d_in[2],
      (const float*)d_in[4], (const float*)d_in[6], (const float*)d_in[8], Wt);
  gemm_qkv<<<dim3(48, 32), 256, 0, stream>>>(
      tempb, spatb, Wt, (const float*)d_in[11], (const float*)d_in[13],
      (const float*)d_in[15], (const float*)d_in[3], (const float*)d_in[5],
      (const float*)d_in[7], Qb, Kb, Vtb);
  flash_attn<<<dim3(16, 64), 256, 0, stream>>>(Qb, Kb, Vtb, Ob);
  gemm_o<<<dim3(16, 32), 256, 0, stream>>>(Ob, Wt, (const float*)d_in[17],
                                           (const float*)d_in[9], temp, spat, projb);
  ln_k<<<2 * NROWS, 256, 0, stream>>>(projb, lng, lnb, out);
}